// Round 1
// baseline (1347.589 us; speedup 1.0000x reference)
//
#include <hip/hip_runtime.h>
#include <hip/hip_bf16.h>
#include <stdint.h>

// Problem constants (Llama4TextExperts: 8 experts, pre-sorted tokens)
#define NE 8
#define HD 2048   // hidden
#define FD 4096   // expert_dim (per gate/up half)
#define TT 1024   // tokens per expert (8192 / 8)

// ---- old fallback path tile config ----
#define BM 128
#define BN 64
#define BK 32
#define LDA 40    // padded leading dim (bf16 elems)

using bf16 = __hip_bfloat16;
typedef __attribute__((ext_vector_type(8))) short bf16x8;
typedef __attribute__((ext_vector_type(4))) float f32x4;

__device__ __forceinline__ bf16 f2b(float x) { return __float2bfloat16(x); }

__device__ __forceinline__ float f4get(const float4 f, int j) {
  return (j == 0) ? f.x : (j == 1) ? f.y : (j == 2) ? f.z : f.w;
}

// async global -> LDS, 16B per lane (HW dest = uniform base + lane*16)
__device__ __forceinline__ void gload16(const void* g, void* l) {
  __builtin_amdgcn_global_load_lds(
      (const __attribute__((address_space(1))) unsigned int*)g,
      (__attribute__((address_space(3))) unsigned int*)l, 16, 0, 0);
}

// ===========================================================================
// NEW PATH
// Swizzle convention (all bf16 operands): within each 128B (64-elem) k-chunk
// of a row, the 16B block at logical index b is STORED at position b ^ (row&7).
// GEMMs stage one 128B chunk/row per K-step linearly via global_load_lds and
// apply the same XOR on ds_read -> conflict-free (2-way) b128 reads.
// ===========================================================================

// X (8192,2048) fp32 -> Xb bf16, swizzled. one 16B out-block per thread.
__global__ void cvt_swz_x(const float* __restrict__ X, bf16* __restrict__ Xb) {
  const int bid = blockIdx.x * 256 + threadIdx.x;
  const int row = bid >> 8;        // 256 blocks of 8 elems per 2048-row
  const int j = bid & 255;
  const float* src = X + (size_t)row * HD + j * 8;
  const float4 v0 = *reinterpret_cast<const float4*>(src);
  const float4 v1 = *reinterpret_cast<const float4*>(src + 4);
  union { bf16 h[8]; uint4 u; } pk;
  pk.h[0] = f2b(v0.x); pk.h[1] = f2b(v0.y); pk.h[2] = f2b(v0.z); pk.h[3] = f2b(v0.w);
  pk.h[4] = f2b(v1.x); pk.h[5] = f2b(v1.y); pk.h[6] = f2b(v1.z); pk.h[7] = f2b(v1.w);
  const int chunk = j >> 3, b = j & 7;
  *reinterpret_cast<uint4*>(reinterpret_cast<char*>(Xb) + (size_t)row * (HD * 2) +
                            chunk * 128 + ((b ^ (row & 7)) << 4)) = pk.u;
}

// W (E,K,N) fp32 -> Wt (E,N,K) bf16, swizzled. 64x64 tile per block.
__global__ void transp_cvt_swz(const float* __restrict__ W, bf16* __restrict__ Wt,
                               int K, int N) {
  __shared__ bf16 T[64][68];  // [n][k], 136B rows: b64-friendly, ~2-way max
  const int e = blockIdx.z;
  const int n0 = blockIdx.x * 64;
  const int k0 = blockIdx.y * 64;
  const float* We = W + (size_t)e * K * N;
  bf16* Wte = Wt + (size_t)e * N * K;
  const int tid = threadIdx.x;
  const int kq = tid >> 4;          // 0..15 -> k = 4*kq + i
  const int n4 = (tid & 15) * 4;    // 0..60
  float4 v[4];
#pragma unroll
  for (int i = 0; i < 4; ++i)
    v[i] = *reinterpret_cast<const float4*>(We + (size_t)(k0 + 4 * kq + i) * N + n0 + n4);
#pragma unroll
  for (int jj = 0; jj < 4; ++jj) {
    union { bf16 h[4]; uint2 u; } pk;
#pragma unroll
    for (int i = 0; i < 4; ++i) pk.h[i] = f2b(f4get(v[i], jj));
    *reinterpret_cast<uint2*>(&T[n4 + jj][4 * kq]) = pk.u;
  }
  __syncthreads();
#pragma unroll
  for (int s = 0; s < 2; ++s) {
    const int sid = s * 256 + tid;   // 512 out-blocks of 16B
    const int n = sid >> 3, c = sid & 7;
    const uint2 lo = *reinterpret_cast<const uint2*>(&T[n][c * 8]);
    const uint2 hi = *reinterpret_cast<const uint2*>(&T[n][c * 8 + 4]);
    uint4 o; o.x = lo.x; o.y = lo.y; o.z = hi.x; o.w = hi.y;
    *reinterpret_cast<uint4*>(reinterpret_cast<char*>(Wte) + (size_t)(n0 + n) * K * 2 +
                              (size_t)(k0 >> 6) * 128 + ((c ^ (n & 7)) << 4)) = o;
  }
}

// GEMM1 + SwiGLU, bf16 path. BM=128, BN=64 per half, BK=64.
__global__ __launch_bounds__(256, 2) void gemm1_bf16(const bf16* __restrict__ Xb,
                                                     const bf16* __restrict__ W1t,
                                                     bf16* __restrict__ inter) {
  __shared__ bf16 As[128 * 64];   // 128 rows x 128B (chunk), linear
  __shared__ bf16 BgS[64 * 64];
  __shared__ bf16 BuS[64 * 64];
  const int e = blockIdx.z;
  const int m0 = blockIdx.y * 128;
  const int n0 = blockIdx.x * 64;
  const char* Arow = (const char*)(Xb + ((size_t)e * TT + m0) * HD);
  const char* Grow = (const char*)(W1t + ((size_t)e * 2 * FD + n0) * HD);
  const char* Urow = (const char*)(W1t + ((size_t)e * 2 * FD + FD + n0) * HD);
  char* AsB = (char*)As; char* BgB = (char*)BgS; char* BuB = (char*)BuS;

  const int tid = threadIdx.x, lane = tid & 63, wave = tid >> 6;
  const int lrow = lane & 15, quad = lane >> 4;
  const int wm = (wave >> 1) * 64, wn = (wave & 1) * 32;
  const size_t lsrc = (size_t)(lane >> 3) * (HD * 2) + (lane & 7) * 16;

  f32x4 accg[4][2] = {};
  f32x4 accu[4][2] = {};

  for (int k0 = 0; k0 < HD; k0 += 64) {
    const size_t kb = (size_t)k0 * 2;
#pragma unroll
    for (int t = 0; t < 4; ++t) {      // A: 128 rows, 8 rows per instr
      const int r = wave * 32 + t * 8;
      gload16(Arow + (size_t)r * (HD * 2) + kb + lsrc, AsB + r * 128);
    }
#pragma unroll
    for (int t = 0; t < 2; ++t) {      // Bg/Bu: 64 rows each
      const int r = wave * 16 + t * 8;
      gload16(Grow + (size_t)r * (HD * 2) + kb + lsrc, BgB + r * 128);
      gload16(Urow + (size_t)r * (HD * 2) + kb + lsrc, BuB + r * 128);
    }
    __syncthreads();
#pragma unroll
    for (int s = 0; s < 2; ++s) {      // two k-sub-steps of 32
      bf16x8 a[4], bg[2], bu[2];
#pragma unroll
      for (int i = 0; i < 4; ++i) {
        const int r = wm + i * 16 + lrow;
        a[i] = *reinterpret_cast<const bf16x8*>(
            AsB + r * 128 + ((((s << 2) + quad) ^ (r & 7)) << 4));
      }
#pragma unroll
      for (int j = 0; j < 2; ++j) {
        const int n = wn + j * 16 + lrow;
        const int off = (((s << 2) + quad) ^ (n & 7)) << 4;
        bg[j] = *reinterpret_cast<const bf16x8*>(BgB + n * 128 + off);
        bu[j] = *reinterpret_cast<const bf16x8*>(BuB + n * 128 + off);
      }
#pragma unroll
      for (int i = 0; i < 4; ++i)
#pragma unroll
        for (int j = 0; j < 2; ++j) {
          accg[i][j] = __builtin_amdgcn_mfma_f32_16x16x32_bf16(a[i], bg[j], accg[i][j], 0, 0, 0);
          accu[i][j] = __builtin_amdgcn_mfma_f32_16x16x32_bf16(a[i], bu[j], accu[i][j], 0, 0, 0);
        }
    }
    __syncthreads();
  }

  // epilogue: SwiGLU, write inter bf16 SWIZZLED (gemm2 stages it linearly)
  bf16* Ie = inter + (size_t)e * TT * FD;
#pragma unroll
  for (int i = 0; i < 4; ++i)
#pragma unroll
    for (int j = 0; j < 2; ++j)
#pragma unroll
      for (int r = 0; r < 4; ++r) {
        const int row = m0 + wm + i * 16 + quad * 4 + r;
        const int col = n0 + wn + j * 16 + lrow;
        const float g = accg[i][j][r];
        const float u = accu[i][j][r];
        const float sv = g / (1.0f + __expf(-g));
        const int chunk = col >> 6, bb = (col >> 3) & 7, el = col & 7;
        Ie[(size_t)row * FD + (chunk << 6) + ((bb ^ (row & 7)) << 3) + el] = f2b(u * sv);
      }
}

// GEMM2, bf16 path. 128x128 tile, BK=64 (m97 clone).
__global__ __launch_bounds__(256, 2) void gemm2_bf16(const bf16* __restrict__ inter,
                                                     const bf16* __restrict__ W2t,
                                                     float* __restrict__ out) {
  __shared__ bf16 As2[128 * 64];
  __shared__ bf16 Bs2[128 * 64];
  const int e = blockIdx.z;
  const int m0 = blockIdx.y * 128;
  const int n0 = blockIdx.x * 128;
  const char* Arow = (const char*)(inter + ((size_t)e * TT + m0) * FD);
  const char* Brow = (const char*)(W2t + ((size_t)e * HD + n0) * FD);
  char* AsB = (char*)As2; char* BsB = (char*)Bs2;

  const int tid = threadIdx.x, lane = tid & 63, wave = tid >> 6;
  const int lrow = lane & 15, quad = lane >> 4;
  const int wm = (wave >> 1) * 64, wn = (wave & 1) * 64;
  const size_t lsrc = (size_t)(lane >> 3) * (FD * 2) + (lane & 7) * 16;

  f32x4 acc[4][4] = {};

  for (int k0 = 0; k0 < FD; k0 += 64) {
    const size_t kb = (size_t)k0 * 2;
#pragma unroll
    for (int t = 0; t < 4; ++t) {
      const int r = wave * 32 + t * 8;
      gload16(Arow + (size_t)r * (FD * 2) + kb + lsrc, AsB + r * 128);
      gload16(Brow + (size_t)r * (FD * 2) + kb + lsrc, BsB + r * 128);
    }
    __syncthreads();
#pragma unroll
    for (int s = 0; s < 2; ++s) {
      bf16x8 a[4], b[4];
#pragma unroll
      for (int i = 0; i < 4; ++i) {
        const int r = wm + i * 16 + lrow;
        a[i] = *reinterpret_cast<const bf16x8*>(
            AsB + r * 128 + ((((s << 2) + quad) ^ (r & 7)) << 4));
      }
#pragma unroll
      for (int j = 0; j < 4; ++j) {
        const int n = wn + j * 16 + lrow;
        b[j] = *reinterpret_cast<const bf16x8*>(
            BsB + n * 128 + ((((s << 2) + quad) ^ (n & 7)) << 4));
      }
#pragma unroll
      for (int i = 0; i < 4; ++i)
#pragma unroll
        for (int j = 0; j < 4; ++j)
          acc[i][j] = __builtin_amdgcn_mfma_f32_16x16x32_bf16(a[i], b[j], acc[i][j], 0, 0, 0);
    }
    __syncthreads();
  }

  float* Oe = out + ((size_t)e * TT + m0) * HD;
#pragma unroll
  for (int i = 0; i < 4; ++i)
#pragma unroll
    for (int j = 0; j < 4; ++j)
#pragma unroll
      for (int r = 0; r < 4; ++r) {
        const int row = wm + i * 16 + quad * 4 + r;
        const int col = n0 + wn + j * 16 + lrow;
        Oe[(size_t)row * HD + col] = acc[i][j][r];
      }
}

// ===========================================================================
// FALLBACK PATH (prior verified kernel, 1789 us) — used if ws too small
// ===========================================================================
__global__ __launch_bounds__(256, 2) void gemm1_swiglu(const float* __restrict__ X,
                                                       const float* __restrict__ W1,
                                                       bf16* __restrict__ inter) {
  __shared__ bf16 As[BM][LDA];
  __shared__ bf16 Bg[BN][LDA];
  __shared__ bf16 Bu[BN][LDA];

  const int e  = blockIdx.z;
  const int m0 = blockIdx.y * BM;
  const int n0 = blockIdx.x * BN;

  const float* Xe = X + (size_t)e * TT * HD + (size_t)m0 * HD;
  const float* We = W1 + (size_t)e * HD * (2 * FD);

  const int tid  = threadIdx.x;
  const int lane = tid & 63;
  const int wave = tid >> 6;
  const int wm   = (wave >> 1) * 64;
  const int wn   = (wave & 1) * 32;
  const int lrow = lane & 15;
  const int quad = lane >> 4;

  f32x4 accg[4][2] = {};
  f32x4 accu[4][2] = {};

  const int aRow = tid >> 3;
  const int aCol = (tid & 7) * 4;
  const int bK   = tid >> 4;
  const int bN   = (tid & 15) * 4;

  for (int k0 = 0; k0 < HD; k0 += BK) {
#pragma unroll
    for (int p = 0; p < 4; ++p) {
      const int r = p * 32 + aRow;
      const float4 v = *reinterpret_cast<const float4*>(Xe + (size_t)r * HD + k0 + aCol);
      union { bf16 h[4]; uint2 u; } pk;
      pk.h[0] = f2b(v.x); pk.h[1] = f2b(v.y); pk.h[2] = f2b(v.z); pk.h[3] = f2b(v.w);
      *reinterpret_cast<uint2*>(&As[r][aCol]) = pk.u;
    }
#pragma unroll
    for (int p = 0; p < 2; ++p) {
      const int k = p * 16 + bK;
      const float* rowp = We + (size_t)(k0 + k) * (2 * FD) + n0 + bN;
      const float4 vg = *reinterpret_cast<const float4*>(rowp);
      const float4 vu = *reinterpret_cast<const float4*>(rowp + FD);
      Bg[bN + 0][k] = f2b(vg.x); Bg[bN + 1][k] = f2b(vg.y);
      Bg[bN + 2][k] = f2b(vg.z); Bg[bN + 3][k] = f2b(vg.w);
      Bu[bN + 0][k] = f2b(vu.x); Bu[bN + 1][k] = f2b(vu.y);
      Bu[bN + 2][k] = f2b(vu.z); Bu[bN + 3][k] = f2b(vu.w);
    }
    __syncthreads();

    bf16x8 a[4], bg[2], bu[2];
#pragma unroll
    for (int i = 0; i < 4; ++i)
      a[i] = *reinterpret_cast<const bf16x8*>(&As[wm + i * 16 + lrow][quad * 8]);
#pragma unroll
    for (int j = 0; j < 2; ++j) {
      bg[j] = *reinterpret_cast<const bf16x8*>(&Bg[wn + j * 16 + lrow][quad * 8]);
      bu[j] = *reinterpret_cast<const bf16x8*>(&Bu[wn + j * 16 + lrow][quad * 8]);
    }
#pragma unroll
    for (int i = 0; i < 4; ++i) {
#pragma unroll
      for (int j = 0; j < 2; ++j) {
        accg[i][j] = __builtin_amdgcn_mfma_f32_16x16x32_bf16(a[i], bg[j], accg[i][j], 0, 0, 0);
        accu[i][j] = __builtin_amdgcn_mfma_f32_16x16x32_bf16(a[i], bu[j], accu[i][j], 0, 0, 0);
      }
    }
    __syncthreads();
  }

  bf16* Ie = inter + (size_t)e * TT * FD;
#pragma unroll
  for (int i = 0; i < 4; ++i) {
#pragma unroll
    for (int j = 0; j < 2; ++j) {
      const int row = m0 + wm + i * 16 + quad * 4;
      const int col = n0 + wn + j * 16 + lrow;
#pragma unroll
      for (int r = 0; r < 4; ++r) {
        const float g = accg[i][j][r];
        const float u = accu[i][j][r];
        const float s = g / (1.0f + __expf(-g));
        Ie[(size_t)(row + r) * FD + col] = f2b(u * s);
      }
    }
  }
}

__global__ __launch_bounds__(256, 2) void gemm2(const bf16* __restrict__ inter,
                                                const float* __restrict__ W2,
                                                float* __restrict__ out) {
  __shared__ bf16 As[BM][LDA];
  __shared__ bf16 Bs[BN][LDA];

  const int e  = blockIdx.z;
  const int m0 = blockIdx.y * BM;
  const int n0 = blockIdx.x * BN;

  const bf16* Ie = inter + (size_t)e * TT * FD + (size_t)m0 * FD;
  const float* We = W2 + (size_t)e * FD * HD;
  float* Oe = out + (size_t)e * TT * HD + (size_t)m0 * HD;

  const int tid  = threadIdx.x;
  const int lane = tid & 63;
  const int wave = tid >> 6;
  const int wm   = (wave >> 1) * 64;
  const int wn   = (wave & 1) * 32;
  const int lrow = lane & 15;
  const int quad = lane >> 4;

  f32x4 acc[4][2] = {};

  const int aRow = tid >> 2;
  const int aK8  = (tid & 3) * 8;
  const int bK   = tid >> 4;
  const int bN   = (tid & 15) * 4;

  for (int k0 = 0; k0 < FD; k0 += BK) {
#pragma unroll
    for (int p = 0; p < 2; ++p) {
      const int r = p * 64 + aRow;
      const uint4 v = *reinterpret_cast<const uint4*>(Ie + (size_t)r * FD + k0 + aK8);
      *reinterpret_cast<uint4*>(&As[r][aK8]) = v;
    }
#pragma unroll
    for (int p = 0; p < 2; ++p) {
      const int k = p * 16 + bK;
      const float4 v = *reinterpret_cast<const float4*>(We + (size_t)(k0 + k) * HD + n0 + bN);
      Bs[bN + 0][k] = f2b(v.x); Bs[bN + 1][k] = f2b(v.y);
      Bs[bN + 2][k] = f2b(v.z); Bs[bN + 3][k] = f2b(v.w);
    }
    __syncthreads();

    bf16x8 a[4], b[2];
#pragma unroll
    for (int i = 0; i < 4; ++i)
      a[i] = *reinterpret_cast<const bf16x8*>(&As[wm + i * 16 + lrow][quad * 8]);
#pragma unroll
    for (int j = 0; j < 2; ++j)
      b[j] = *reinterpret_cast<const bf16x8*>(&Bs[wn + j * 16 + lrow][quad * 8]);
#pragma unroll
    for (int i = 0; i < 4; ++i) {
#pragma unroll
      for (int j = 0; j < 2; ++j) {
        acc[i][j] = __builtin_amdgcn_mfma_f32_16x16x32_bf16(a[i], b[j], acc[i][j], 0, 0, 0);
      }
    }
    __syncthreads();
  }

#pragma unroll
  for (int i = 0; i < 4; ++i) {
#pragma unroll
    for (int j = 0; j < 2; ++j) {
      const int row = wm + i * 16 + quad * 4;
      const int col = n0 + wn + j * 16 + lrow;
#pragma unroll
      for (int r = 0; r < 4; ++r) {
        Oe[(size_t)(row + r) * HD + col] = acc[i][j][r];
      }
    }
  }
}

// ---------------------------------------------------------------------------
extern "C" void kernel_launch(void* const* d_in, const int* in_sizes, int n_in,
                              void* d_out, int out_size, void* d_ws, size_t ws_size,
                              hipStream_t stream) {
  (void)in_sizes; (void)n_in; (void)out_size;
  const float* X  = (const float*)d_in[0];   // (8192, 2048) fp32
  const float* W1 = (const float*)d_in[1];   // (8, 2048, 8192) fp32
  const float* W2 = (const float*)d_in[2];   // (8, 4096, 2048) fp32
  float* out = (float*)d_out;                // (8192, 2048) fp32

  const size_t SZ_XB  = (size_t)NE * TT * HD * 2;        //  32 MiB
  const size_t SZ_W1T = (size_t)NE * (2 * FD) * HD * 2;  // 256 MiB
  const size_t SZ_W2T = (size_t)NE * HD * FD * 2;        // 128 MiB
  const size_t SZ_INT = (size_t)NE * TT * FD * 2;        //  64 MiB
  const size_t NEED   = SZ_XB + SZ_W1T + SZ_W2T + SZ_INT;

  if (ws_size >= NEED) {
    bf16* Xb    = (bf16*)d_ws;
    bf16* W1t   = (bf16*)((char*)d_ws + SZ_XB);
    bf16* W2t   = (bf16*)((char*)d_ws + SZ_XB + SZ_W1T);
    bf16* inter = (bf16*)((char*)d_ws + SZ_XB + SZ_W1T + SZ_W2T);

    hipLaunchKernelGGL(cvt_swz_x, dim3((NE * TT * HD / 8) / 256), dim3(256), 0, stream, X, Xb);
    hipLaunchKernelGGL(transp_cvt_swz, dim3((2 * FD) / 64, HD / 64, NE), dim3(256), 0, stream,
                       W1, W1t, HD, 2 * FD);
    hipLaunchKernelGGL(transp_cvt_swz, dim3(HD / 64, FD / 64, NE), dim3(256), 0, stream,
                       W2, W2t, FD, HD);
    hipLaunchKernelGGL(gemm1_bf16, dim3(FD / 64, TT / 128, NE), dim3(256), 0, stream,
                       Xb, W1t, inter);
    hipLaunchKernelGGL(gemm2_bf16, dim3(HD / 128, TT / 128, NE), dim3(256), 0, stream,
                       inter, W2t, out);
  } else {
    // fallback: prior verified path (needs only 64 MiB of workspace)
    bf16* inter = (bf16*)d_ws;
    dim3 blk(256, 1, 1);
    hipLaunchKernelGGL(gemm1_swiglu, dim3(FD / BN, TT / BM, NE), blk, 0, stream, X, W1, inter);
    hipLaunchKernelGGL(gemm2, dim3(HD / BN, TT / BM, NE), blk, 0, stream, inter, W2, out);
  }
}